// Round 16
// baseline (163.210 us; speedup 1.0000x reference)
//
#include <hip/hip_runtime.h>

constexpr int N_NODES = 50000;
constexpr int N_REL   = 4;
constexpr int EMBD    = 128;
constexpr int N_HEAD  = 4;
constexpr int HS      = 32;
constexpr int N_EDGE  = 400000;
constexpr int N_ROWS  = N_REL * N_NODES;        // 200000 segment rows
constexpr int N_SBLK  = 196;                    // scan blocks (1024 rows each)

typedef __attribute__((ext_vector_type(8))) short bf16x8;
typedef __attribute__((ext_vector_type(4))) float f32x4;
typedef unsigned short ushort_t;
typedef unsigned int   uint_t;

__device__ __forceinline__ ushort_t f2b(float f) {
    unsigned int u = __float_as_uint(f);
    u += 0x7FFF + ((u >> 16) & 1);   // round-to-nearest-even
    return (ushort_t)(u >> 16);
}
__device__ __forceinline__ float lo_bf(uint_t u) {   // bf16 pair: low elem
    return __uint_as_float(u << 16);
}
__device__ __forceinline__ float hi_bf(uint_t u) {   // bf16 pair: high elem
    return __uint_as_float(u & 0xFFFF0000u);
}

// ---------------------------------------------------------------------------
// prep (fused): XB = bf16(x), HIST = 0, Ct = tokeys^T toqueries (per r,h),
// Mb = U·BD(tovals). KNOWN GOOD (r13-15).
// ---------------------------------------------------------------------------
__global__ __launch_bounds__(256) void prep_kernel(
    const float* __restrict__ x,
    const float* __restrict__ tk, const float* __restrict__ tq,
    const float* __restrict__ tv, const float* __restrict__ un,
    ushort_t* __restrict__ XB, int* __restrict__ HIST,
    ushort_t* __restrict__ Ct, ushort_t* __restrict__ Mb)
{
    int idx = blockIdx.x * 256 + threadIdx.x;      // grid 25320 = 6481920 threads
    if (idx < N_NODES * EMBD) {
        XB[idx] = f2b(x[idx]);
        if (idx < N_ROWS) HIST[idx] = 0;
    } else {
        int jj = idx - N_NODES * EMBD;             // < 81920
        if (jj < 16384) {
            int a = jj & 31, b = (jj >> 5) & 31, rh = jj >> 10;   // rh = r*4+h
            const float* tks = tk + rh * 1024;     // [s][a]
            const float* tqs = tq + rh * 1024;     // [s][b]
            float acc = 0.f;
            #pragma unroll
            for (int s = 0; s < 32; s++) acc += tks[s * 32 + a] * tqs[s * 32 + b];
            Ct[jj] = f2b(acc);                     // (rh*32 + b)*32 + a
        } else {
            int j  = jj - 16384;                   // Mb flat: [r][i][jc]
            int jc = j & 127, i = (j >> 7) & 127, r = j >> 14;
            int h = jc >> 5, k = jc & 31;
            const float* us  = un + ((size_t)(r * 128 + i)) * 128 + h * 32;
            const float* tvs = tv + (r * 4 + h) * 1024 + k;
            float acc = 0.f;
            #pragma unroll
            for (int s = 0; s < 32; s++) acc += us[s] * tvs[s * 32];
            Mb[j] = f2b(acc);
        }
    }
}

// ---------------------------------------------------------------------------
// CSR build: histogram -> 3-phase deterministic scan -> scatter. KNOWN GOOD.
// ---------------------------------------------------------------------------
__global__ __launch_bounds__(256) void hist_kernel(
    const int* __restrict__ esub, const int* __restrict__ epred, int* __restrict__ HIST)
{
    int e = blockIdx.x * 256 + threadIdx.x;
    if (e < N_EDGE) atomicAdd(&HIST[epred[e] * N_NODES + esub[e]], 1);
}

__global__ __launch_bounds__(256) void scan_p1(      // per-block totals
    const int* __restrict__ HIST, int* __restrict__ SUMS)
{
    int b = blockIdx.x, t = threadIdx.x;
    int base = b * 1024 + t * 4;
    int s = 0;
    #pragma unroll
    for (int k = 0; k < 4; k++) if (base + k < N_ROWS) s += HIST[base + k];
    __shared__ int red[256];
    red[t] = s; __syncthreads();
    for (int st = 128; st > 0; st >>= 1) {
        if (t < st) red[t] += red[t + st];
        __syncthreads();
    }
    if (t == 0) SUMS[b] = red[0];
}

__global__ __launch_bounds__(256) void scan_p2(      // scan the 196 totals
    const int* __restrict__ SUMS, int* __restrict__ SOFF, int* __restrict__ OFFS)
{
    int t = threadIdx.x;
    __shared__ int sh[256];
    int o = (t < N_SBLK) ? SUMS[t] : 0;
    sh[t] = o; __syncthreads();
    for (int st = 1; st < 256; st <<= 1) {
        int v = (t >= st) ? sh[t - st] : 0;
        __syncthreads();
        sh[t] += v;
        __syncthreads();
    }
    if (t < N_SBLK) SOFF[t] = sh[t] - o;             // exclusive
    if (t == 0)  OFFS[N_ROWS] = sh[255];             // total == N_EDGE
}

__global__ __launch_bounds__(256) void scan_p3(      // full exclusive scan (+CURSOR)
    const int* __restrict__ HIST, const int* __restrict__ SOFF,
    int* __restrict__ OFFS, int* __restrict__ CURSOR)
{
    int b = blockIdx.x, t = threadIdx.x;
    int base = b * 1024 + t * 4;
    int v[4], tot = 0;
    #pragma unroll
    for (int k = 0; k < 4; k++) {
        v[k] = (base + k < N_ROWS) ? HIST[base + k] : 0;
        tot += v[k];
    }
    __shared__ int sh[256];
    sh[t] = tot; __syncthreads();
    for (int st = 1; st < 256; st <<= 1) {
        int q = (t >= st) ? sh[t - st] : 0;
        __syncthreads();
        sh[t] += q;
        __syncthreads();
    }
    int run = SOFF[b] + (sh[t] - tot);
    #pragma unroll
    for (int k = 0; k < 4; k++) {
        if (base + k < N_ROWS) { OFFS[base + k] = run; CURSOR[base + k] = run; run += v[k]; }
    }
}

__global__ __launch_bounds__(256) void scatter_kernel(
    const int* __restrict__ esub, const int* __restrict__ epred, const int* __restrict__ eobj,
    int* __restrict__ CURSOR, int* __restrict__ OBJS)
{
    int e = blockIdx.x * 256 + threadIdx.x;
    if (e < N_EDGE) {
        int row = epred[e] * N_NODES + esub[e];
        int pos = atomicAdd(&CURSOR[row], 1);
        OBJS[pos] = eobj[e];                       // store obj, not edge id
    }
}

// ---------------------------------------------------------------------------
// FUSED projection + dot + softmax + aggregate. Block = 16 nodes x 4 relations
// = 64 rows. KT NEVER TOUCHES GLOBAL MEMORY (r15 round-tripped 102MB of it):
//  Phase 1 (proj): stage 16 x-rows in LDS; wave w computes Kt for relation w
//    via 8 MFMAs (fragment maps + Ct addressing proven r12-15, n-tile=16),
//    D-fragments -> 16KB LDS kt buffer.
//  Phase 2 (agg): r15's half-wave-per-row body verbatim — lanes 0-31 / 32-63
//    each own a row (uint2 = 4 elems/lane), 3-shfl butterfly per head,
//    one gather instruction serves two edges, 2-edge unroll per half.
//    Kt comes from a conflict-free 8B LDS read. Each half-wave walks its 8
//    sequential rows (row_local = hw*8+k; r = rl>>4, nl = rl&15).
// LDS ~20.3KB -> 7 blocks/CU (28 waves, above r15-agg's 60% occupancy).
// ---------------------------------------------------------------------------
__global__ __launch_bounds__(256) void projagg_fused(
    const ushort_t* __restrict__ XB, const ushort_t* __restrict__ Ct,
    const int* __restrict__ OFFS, const int* __restrict__ OBJS,
    const uint2* __restrict__ XB128, uint2* __restrict__ AGG128)
{
    __shared__ ushort_t xs[16 * 136];    // x tile: 16 nodes (pad 136 as proven)
    __shared__ ushort_t kt[64 * 128];    // Kt for 64 rows [r*16+nl][128]

    const int t    = threadIdx.x;
    const int lane = t & 63;
    const int w    = t >> 6;             // wave 0..3 = relation
    const int n0   = blockIdx.x * 16;    // grid 3125: 16 | 50000 exact

    {   // stage xs: 16 nodes x 128 bf16 = 4KB = 256 threads x 16B (one shot)
        const uint4* x4 = (const uint4*)(XB + (size_t)n0 * 128);
        int nn = t >> 4, c = t & 15;
        *(uint4*)&xs[nn * 136 + c * 8] = x4[t];
    }
    __syncthreads();

    {   // proj: wave w = relation w, 16 nodes, 8 MFMAs
        const int row  = lane & 15;
        const int kg   = lane >> 4;
        const int rgrp = lane >> 4;
        f32x4 acc[8];
        #pragma unroll
        for (int f = 0; f < 8; f++) {
            const int h = f >> 1;
            bf16x8 a = *(const bf16x8*)&xs[row * 136 + h * 32 + kg * 8];
            const ushort_t* bp = Ct + (((w * 4 + h) * 32 + (f & 1) * 16 + row) * 32) + kg * 8;
            bf16x8 b = *(const bf16x8*)bp;
            acc[f] = __builtin_amdgcn_mfma_f32_16x16x32_bf16(
                         a, b, (f32x4){0.f, 0.f, 0.f, 0.f}, 0, 0, 0);
        }
        #pragma unroll
        for (int f = 0; f < 8; f++) {
            #pragma unroll
            for (int reg = 0; reg < 4; reg++)
                kt[(w * 16 + rgrp * 4 + reg) * 128 + f * 16 + row] = f2b(acc[f][reg]);
        }
    }
    __syncthreads();

    // agg: half-wave hw (0..7) handles row_locals hw*8 .. hw*8+7
    const int l5 = lane & 31;
    const int hw = t >> 5;
    #pragma unroll 1
    for (int k = 0; k < 8; k++) {
        const int rl  = hw * 8 + k;
        const int row = (rl >> 4) * N_NODES + n0 + (rl & 15);
        const int beg = OFFS[row], end = OFFS[row + 1];   // half-uniform
        const bool has = beg < end;

        float k0 = 0.f, k1 = 0.f, k2 = 0.f, k3 = 0.f;
        if (has) {
            uint2 ku = *(const uint2*)&kt[rl * 128 + l5 * 4];
            k0 = lo_bf(ku.x); k1 = hi_bf(ku.x); k2 = lo_bf(ku.y); k3 = hi_bf(ku.y);
        }

        float a0 = 0.f, a1 = 0.f, a2 = 0.f, a3 = 0.f, seg = 0.f;
        int it = beg;
        while (__any(it < end)) {                   // wave-uniform loop bound
            const bool d0 = it < end;               // half-uniform guards
            const bool d1 = it + 1 < end;
            uint2 xu0 = make_uint2(0u, 0u), xu1 = make_uint2(0u, 0u);
            if (d0) xu0 = XB128[(unsigned)OBJS[it] * 32u + l5];
            if (d1) xu1 = XB128[(unsigned)OBJS[it + 1] * 32u + l5];

            float x00 = lo_bf(xu0.x), x01 = hi_bf(xu0.x), x02 = lo_bf(xu0.y), x03 = hi_bf(xu0.y);
            float x10 = lo_bf(xu1.x), x11 = hi_bf(xu1.x), x12 = lo_bf(xu1.y), x13 = hi_bf(xu1.y);

            float p0 = k0 * x00 + k1 * x01 + k2 * x02 + k3 * x03;
            float p1 = k0 * x10 + k1 * x11 + k2 * x12 + k3 * x13;
            p0 += __shfl_xor(p0, 1, 64); p1 += __shfl_xor(p1, 1, 64);
            p0 += __shfl_xor(p0, 2, 64); p1 += __shfl_xor(p1, 2, 64);
            p0 += __shfl_xor(p0, 4, 64); p1 += __shfl_xor(p1, 4, 64);
            float ex0 = __expf(p0), ex1 = __expf(p1);

            int adv = 0;
            if (d0) { a0 += ex0 * x00; a1 += ex0 * x01; a2 += ex0 * x02; a3 += ex0 * x03; seg += ex0; adv = 1; }
            if (d1) { a0 += ex1 * x10; a1 += ex1 * x11; a2 += ex1 * x12; a3 += ex1 * x13; seg += ex1; adv = 2; }
            it += adv;
        }

        uint2 o = make_uint2(0u, 0u);
        if (has) {
            float inv = 1.0f / seg;
            o.x = (uint_t)f2b(a0 * inv) | ((uint_t)f2b(a1 * inv) << 16);
            o.y = (uint_t)f2b(a2 * inv) | ((uint_t)f2b(a3 * inv) << 16);
        }
        AGG128[(unsigned)row * 32u + l5] = o;
    }
}

// ---------------------------------------------------------------------------
// out[n][i] = relu( sum_r sum_j M[r][i][j] * AGGX[r][n][j] )  — bf16 MFMA,
// fp32 accum. KNOWN GOOD (rounds 5-15); B = Mb (U·BD(tovals)).
// ---------------------------------------------------------------------------
__global__ __launch_bounds__(256) void unify_mfma(
    const ushort_t* __restrict__ AGG,
    const ushort_t* __restrict__ Ub, float* __restrict__ out)
{
    __shared__ ushort_t As[64 * 136];    // A tile: [node][k] bf16
    __shared__ ushort_t Bs[128 * 136];   // B tile: [i][k] bf16

    const int t    = threadIdx.x;
    const int lane = t & 63;
    const int w    = t >> 6;
    const int n0   = blockIdx.x * 64;

    f32x4 acc[8];
    #pragma unroll
    for (int f = 0; f < 8; f++) acc[f] = (f32x4){0.f, 0.f, 0.f, 0.f};

    for (int r = 0; r < N_REL; r++) {
        __syncthreads();

        {   // stage A: AGG[r][n0..n0+63][0..127] plain bf16 copy (16B chunks)
            const uint4* a4 = (const uint4*)(AGG + ((size_t)r * N_NODES + n0) * 128);
            for (int idx = t; idx < 64 * 16; idx += 256) {
                int nn = idx >> 4, c = idx & 15;
                uint4 v = make_uint4(0, 0, 0, 0);
                if (n0 + nn < N_NODES) v = a4[idx];
                *(uint4*)&As[nn * 136 + c * 8] = v;
            }
        }
        {   // stage B: Mb[r] straight copy (L2-hot)
            const uint4* u4 = (const uint4*)(Ub + (size_t)r * 128 * 128);
            for (int idx = t; idx < 128 * 16; idx += 256) {
                int i = idx >> 4, c = idx & 15;
                *(uint4*)&Bs[i * 136 + c * 8] = u4[idx];
            }
        }
        __syncthreads();

        const int row = lane & 15;     // A row / B col
        const int kg  = lane >> 4;     // k-group
        #pragma unroll
        for (int ks = 0; ks < 4; ks++) {
            const int kofs = ks * 32 + kg * 8;
            bf16x8 a = *(const bf16x8*)&As[(w * 16 + row) * 136 + kofs];
            #pragma unroll
            for (int f = 0; f < 8; f++) {
                bf16x8 b = *(const bf16x8*)&Bs[(f * 16 + row) * 136 + kofs];
                acc[f] = __builtin_amdgcn_mfma_f32_16x16x32_bf16(a, b, acc[f], 0, 0, 0);
            }
        }
    }

    const int col  = lane & 15;
    const int rgrp = lane >> 4;
    #pragma unroll
    for (int f = 0; f < 8; f++) {
        #pragma unroll
        for (int reg = 0; reg < 4; reg++) {
            int n = n0 + w * 16 + rgrp * 4 + reg;
            if (n < N_NODES)
                out[(size_t)n * 128 + f * 16 + col] = fmaxf(acc[f][reg], 0.f);
        }
    }
}

extern "C" void kernel_launch(void* const* d_in, const int* in_sizes, int n_in,
                              void* d_out, int out_size, void* d_ws, size_t ws_size,
                              hipStream_t stream)
{
    const float* x  = (const float*)d_in[0];
    const float* tk = (const float*)d_in[1];
    const float* tq = (const float*)d_in[2];
    const float* tv = (const float*)d_in[3];
    const float* un = (const float*)d_in[4];
    const int* esub  = (const int*)d_in[5];
    const int* epred = (const int*)d_in[6];
    const int* eobj  = (const int*)d_in[7];
    float* out = (float*)d_out;

    // Workspace layout (bytes), offsets identical to r12-15 (KT slot now
    // unused — Kt lives in LDS only):
    //   (unused, was KT)                                 @ 0            (51,200,000)
    //   XB:   [N][128] bf16 (x cast — the gather target) @ 51,200,000   (12,800,000)
    //   AGG:  [R*N][128] bf16 (x-space aggregates)       @ 64,000,000   (51,200,000)
    //   HIST/CURSOR: [200000] int                        @ 115,200,000  (   800,000)
    //   SUMS: [196] int (pad 4096)                       @ 116,000,000  (     4,096)
    //   SOFF: [196] int (pad 4096)                       @ 116,004,096  (     4,096)
    //   OFFS: [200001] int                               @ 116,008,192  (   800,004 pad)
    //   OBJS: [400000] int                               @ 116,816,000  ( 1,600,000)
    //   Mb:   [R][128][128] bf16 (U·BD(tovals))          @ 118,416,000  (   131,072)
    //   Ct:   [R][H][32][32] bf16 (K^T Q bilinear)       @ 118,547,072  (    32,768)
    char* ws = (char*)d_ws;
    ushort_t* XB  = (ushort_t*)(ws + 51200000);
    ushort_t* AGG = (ushort_t*)(ws + 64000000);
    int*      HIST= (int*)     (ws + 115200000);   // doubles as CURSOR
    int*      SUMS= (int*)     (ws + 116000000);
    int*      SOFF= (int*)     (ws + 116004096);
    int*      OFFS= (int*)     (ws + 116008192);
    int*      OBJS= (int*)     (ws + 116816000);
    ushort_t* Mb  = (ushort_t*)(ws + 118416000);
    ushort_t* Ct  = (ushort_t*)(ws + 118547072);

    // prep (fused): x cast + HIST zero + Ct/Mb small-matrix products
    prep_kernel<<<(N_NODES * EMBD + 81920) / 256, 256, 0, stream>>>(
        x, tk, tq, tv, un, XB, HIST, Ct, Mb);

    // CSR build
    hist_kernel<<<(N_EDGE + 255) / 256, 256, 0, stream>>>(esub, epred, HIST);
    scan_p1<<<N_SBLK, 256, 0, stream>>>(HIST, SUMS);
    scan_p2<<<1, 256, 0, stream>>>(SUMS, SOFF, OFFS);
    scan_p3<<<N_SBLK, 256, 0, stream>>>(HIST, SOFF, OFFS, HIST);  // OFFS + CURSOR
    scatter_kernel<<<(N_EDGE + 255) / 256, 256, 0, stream>>>(esub, epred, eobj, HIST, OBJS);

    // fused proj + bilinear-dot + softmax + x-space aggregate (Kt in LDS only)
    projagg_fused<<<N_NODES / 16, 256, 0, stream>>>(XB, Ct, OFFS, OBJS,
                                                    (const uint2*)XB, (uint2*)AGG);

    unify_mfma<<<(N_NODES + 63) / 64, 256, 0, stream>>>(AGG, Mb, out);
}

// Round 17
// 155.193 us; speedup vs baseline: 1.0517x; 1.0517x over previous
//
#include <hip/hip_runtime.h>

constexpr int N_NODES = 50000;
constexpr int N_REL   = 4;
constexpr int EMBD    = 128;
constexpr int N_HEAD  = 4;
constexpr int HS      = 32;
constexpr int N_EDGE  = 400000;
constexpr int N_ROWS  = N_REL * N_NODES;        // 200000 segment rows
constexpr int N_SBLK  = 196;                    // scan blocks (1024 rows each)

typedef __attribute__((ext_vector_type(8))) short bf16x8;
typedef __attribute__((ext_vector_type(4))) float f32x4;
typedef unsigned short ushort_t;
typedef unsigned int   uint_t;

__device__ __forceinline__ ushort_t f2b(float f) {
    unsigned int u = __float_as_uint(f);
    u += 0x7FFF + ((u >> 16) & 1);   // round-to-nearest-even
    return (ushort_t)(u >> 16);
}
__device__ __forceinline__ float lo_bf(uint_t u) {   // bf16 pair: low elem
    return __uint_as_float(u << 16);
}
__device__ __forceinline__ float hi_bf(uint_t u) {   // bf16 pair: high elem
    return __uint_as_float(u & 0xFFFF0000u);
}

// ---------------------------------------------------------------------------
// prep (fused): XB = bf16(x), HIST = 0, Ct = tokeys^T toqueries (per r,h),
// Mb = U·BD(tovals). KNOWN GOOD (r13-16).
// ---------------------------------------------------------------------------
__global__ __launch_bounds__(256) void prep_kernel(
    const float* __restrict__ x,
    const float* __restrict__ tk, const float* __restrict__ tq,
    const float* __restrict__ tv, const float* __restrict__ un,
    ushort_t* __restrict__ XB, int* __restrict__ HIST,
    ushort_t* __restrict__ Ct, ushort_t* __restrict__ Mb)
{
    int idx = blockIdx.x * 256 + threadIdx.x;      // grid 25320 = 6481920 threads
    if (idx < N_NODES * EMBD) {
        XB[idx] = f2b(x[idx]);
        if (idx < N_ROWS) HIST[idx] = 0;
    } else {
        int jj = idx - N_NODES * EMBD;             // < 81920
        if (jj < 16384) {
            int a = jj & 31, b = (jj >> 5) & 31, rh = jj >> 10;   // rh = r*4+h
            const float* tks = tk + rh * 1024;     // [s][a]
            const float* tqs = tq + rh * 1024;     // [s][b]
            float acc = 0.f;
            #pragma unroll
            for (int s = 0; s < 32; s++) acc += tks[s * 32 + a] * tqs[s * 32 + b];
            Ct[jj] = f2b(acc);                     // (rh*32 + b)*32 + a
        } else {
            int j  = jj - 16384;                   // Mb flat: [r][i][jc]
            int jc = j & 127, i = (j >> 7) & 127, r = j >> 14;
            int h = jc >> 5, k = jc & 31;
            const float* us  = un + ((size_t)(r * 128 + i)) * 128 + h * 32;
            const float* tvs = tv + (r * 4 + h) * 1024 + k;
            float acc = 0.f;
            #pragma unroll
            for (int s = 0; s < 32; s++) acc += us[s] * tvs[s * 32];
            Mb[j] = f2b(acc);
        }
    }
}

// ---------------------------------------------------------------------------
// CSR build: histogram -> 3-phase deterministic scan -> scatter. KNOWN GOOD.
// ---------------------------------------------------------------------------
__global__ __launch_bounds__(256) void hist_kernel(
    const int* __restrict__ esub, const int* __restrict__ epred, int* __restrict__ HIST)
{
    int e = blockIdx.x * 256 + threadIdx.x;
    if (e < N_EDGE) atomicAdd(&HIST[epred[e] * N_NODES + esub[e]], 1);
}

__global__ __launch_bounds__(256) void scan_p1(      // per-block totals
    const int* __restrict__ HIST, int* __restrict__ SUMS)
{
    int b = blockIdx.x, t = threadIdx.x;
    int base = b * 1024 + t * 4;
    int s = 0;
    #pragma unroll
    for (int k = 0; k < 4; k++) if (base + k < N_ROWS) s += HIST[base + k];
    __shared__ int red[256];
    red[t] = s; __syncthreads();
    for (int st = 128; st > 0; st >>= 1) {
        if (t < st) red[t] += red[t + st];
        __syncthreads();
    }
    if (t == 0) SUMS[b] = red[0];
}

__global__ __launch_bounds__(256) void scan_p2(      // scan the 196 totals
    const int* __restrict__ SUMS, int* __restrict__ SOFF, int* __restrict__ OFFS)
{
    int t = threadIdx.x;
    __shared__ int sh[256];
    int o = (t < N_SBLK) ? SUMS[t] : 0;
    sh[t] = o; __syncthreads();
    for (int st = 1; st < 256; st <<= 1) {
        int v = (t >= st) ? sh[t - st] : 0;
        __syncthreads();
        sh[t] += v;
        __syncthreads();
    }
    if (t < N_SBLK) SOFF[t] = sh[t] - o;             // exclusive
    if (t == 0)  OFFS[N_ROWS] = sh[255];             // total == N_EDGE
}

__global__ __launch_bounds__(256) void scan_p3(      // full exclusive scan (+CURSOR)
    const int* __restrict__ HIST, const int* __restrict__ SOFF,
    int* __restrict__ OFFS, int* __restrict__ CURSOR)
{
    int b = blockIdx.x, t = threadIdx.x;
    int base = b * 1024 + t * 4;
    int v[4], tot = 0;
    #pragma unroll
    for (int k = 0; k < 4; k++) {
        v[k] = (base + k < N_ROWS) ? HIST[base + k] : 0;
        tot += v[k];
    }
    __shared__ int sh[256];
    sh[t] = tot; __syncthreads();
    for (int st = 1; st < 256; st <<= 1) {
        int q = (t >= st) ? sh[t - st] : 0;
        __syncthreads();
        sh[t] += q;
        __syncthreads();
    }
    int run = SOFF[b] + (sh[t] - tot);
    #pragma unroll
    for (int k = 0; k < 4; k++) {
        if (base + k < N_ROWS) { OFFS[base + k] = run; CURSOR[base + k] = run; run += v[k]; }
    }
}

__global__ __launch_bounds__(256) void scatter_kernel(
    const int* __restrict__ esub, const int* __restrict__ epred, const int* __restrict__ eobj,
    int* __restrict__ CURSOR, int* __restrict__ OBJS)
{
    int e = blockIdx.x * 256 + threadIdx.x;
    if (e < N_EDGE) {
        int row = epred[e] * N_NODES + esub[e];
        int pos = atomicAdd(&CURSOR[row], 1);
        OBJS[pos] = eobj[e];                       // store obj, not edge id
    }
}

// ---------------------------------------------------------------------------
// FUSED projection + dot + softmax + aggregate, 1024-thread blocks (16 waves).
// Block = 16 nodes x 4 relations = 64 rows. Kt never touches global memory.
//  Phase 1 (proj, ALL 16 waves): wave w -> relation r=w>>2, f-pair fp=w&3.
//    Both f's share h=fp -> ONE A-frag load + 2 MFMAs per wave (fragment maps
//    proven r5-16). D -> kt LDS, padded stride 132: store banks land at
//    kg*8 offsets (264B row = 66 words, 66%32=2) — conflict-free.
//  Phase 2 (agg): 32 half-waves x 2 serial rows (rl = hw, hw+32): r15's
//    edge-loop body verbatim, Kt from an 8B conflict-free LDS read.
// Occupancy: 2 blocks/CU x 16 waves = 32 waves/CU (100%; r16's shape got 38%).
// ---------------------------------------------------------------------------
__global__ __launch_bounds__(1024) void projagg_fused(
    const ushort_t* __restrict__ XB, const ushort_t* __restrict__ Ct,
    const int* __restrict__ OFFS, const int* __restrict__ OBJS,
    const uint2* __restrict__ XB128, uint2* __restrict__ AGG128)
{
    __shared__ __align__(16) ushort_t xs[16 * 136];   // x tile, proven pad
    __shared__ __align__(16) ushort_t kt[64 * 132];   // Kt[rl][128], pad 132

    const int t    = threadIdx.x;        // 0..1023
    const int lane = t & 63;
    const int w    = t >> 6;             // wave 0..15
    const int n0   = blockIdx.x * 16;    // grid 3125: 16 | 50000 exact

    if (t < 256) {   // stage xs: 16 nodes x 128 bf16 = 4KB (one shot)
        const uint4* x4 = (const uint4*)(XB + (size_t)n0 * 128);
        int nn = t >> 4, c = t & 15;
        *(uint4*)&xs[nn * 136 + c * 8] = x4[t];
    }
    __syncthreads();

    {   // proj: wave w -> (r = w>>2, fp = w&3); h = fp for both f's
        const int r   = w >> 2;
        const int fp  = w & 3;
        const int row = lane & 15;
        const int kg  = lane >> 4;
        bf16x8 a = *(const bf16x8*)&xs[row * 136 + fp * 32 + kg * 8];
        #pragma unroll
        for (int j = 0; j < 2; j++) {
            const int f = fp * 2 + j;
            const ushort_t* bp = Ct + (((r * 4 + fp) * 32 + j * 16 + row) * 32) + kg * 8;
            bf16x8 b = *(const bf16x8*)bp;
            f32x4 acc = __builtin_amdgcn_mfma_f32_16x16x32_bf16(
                            a, b, (f32x4){0.f, 0.f, 0.f, 0.f}, 0, 0, 0);
            #pragma unroll
            for (int reg = 0; reg < 4; reg++)
                kt[(r * 16 + kg * 4 + reg) * 132 + f * 16 + row] = f2b(acc[reg]);
        }
    }
    __syncthreads();

    // agg: half-wave hw (0..31) handles rl = hw and hw+32 (k-loop is
    // wave-uniform; both halves of a wave are always at the same k)
    const int l5 = lane & 31;
    const int hw = t >> 5;
    #pragma unroll 1
    for (int k = 0; k < 2; k++) {
        const int rl  = hw + k * 32;
        const int row = (rl >> 4) * N_NODES + n0 + (rl & 15);
        const int beg = OFFS[row], end = OFFS[row + 1];   // half-uniform
        const bool has = beg < end;

        float k0 = 0.f, k1 = 0.f, k2 = 0.f, k3 = 0.f;
        if (has) {
            uint2 ku = *(const uint2*)&kt[rl * 132 + l5 * 4];
            k0 = lo_bf(ku.x); k1 = hi_bf(ku.x); k2 = lo_bf(ku.y); k3 = hi_bf(ku.y);
        }

        float a0 = 0.f, a1 = 0.f, a2 = 0.f, a3 = 0.f, seg = 0.f;
        int it = beg;
        while (__any(it < end)) {                   // wave-uniform loop bound
            const bool d0 = it < end;               // half-uniform guards
            const bool d1 = it + 1 < end;
            uint2 xu0 = make_uint2(0u, 0u), xu1 = make_uint2(0u, 0u);
            if (d0) xu0 = XB128[(unsigned)OBJS[it] * 32u + l5];
            if (d1) xu1 = XB128[(unsigned)OBJS[it + 1] * 32u + l5];

            float x00 = lo_bf(xu0.x), x01 = hi_bf(xu0.x), x02 = lo_bf(xu0.y), x03 = hi_bf(xu0.y);
            float x10 = lo_bf(xu1.x), x11 = hi_bf(xu1.x), x12 = lo_bf(xu1.y), x13 = hi_bf(xu1.y);

            float p0 = k0 * x00 + k1 * x01 + k2 * x02 + k3 * x03;
            float p1 = k0 * x10 + k1 * x11 + k2 * x12 + k3 * x13;
            p0 += __shfl_xor(p0, 1, 64); p1 += __shfl_xor(p1, 1, 64);
            p0 += __shfl_xor(p0, 2, 64); p1 += __shfl_xor(p1, 2, 64);
            p0 += __shfl_xor(p0, 4, 64); p1 += __shfl_xor(p1, 4, 64);
            float ex0 = __expf(p0), ex1 = __expf(p1);

            int adv = 0;
            if (d0) { a0 += ex0 * x00; a1 += ex0 * x01; a2 += ex0 * x02; a3 += ex0 * x03; seg += ex0; adv = 1; }
            if (d1) { a0 += ex1 * x10; a1 += ex1 * x11; a2 += ex1 * x12; a3 += ex1 * x13; seg += ex1; adv = 2; }
            it += adv;
        }

        uint2 o = make_uint2(0u, 0u);
        if (has) {
            float inv = 1.0f / seg;
            o.x = (uint_t)f2b(a0 * inv) | ((uint_t)f2b(a1 * inv) << 16);
            o.y = (uint_t)f2b(a2 * inv) | ((uint_t)f2b(a3 * inv) << 16);
        }
        AGG128[(unsigned)row * 32u + l5] = o;
    }
}

// ---------------------------------------------------------------------------
// out[n][i] = relu( sum_r sum_j M[r][i][j] * AGGX[r][n][j] )  — bf16 MFMA,
// fp32 accum. KNOWN GOOD (rounds 5-16); B = Mb (U·BD(tovals)).
// ---------------------------------------------------------------------------
__global__ __launch_bounds__(256) void unify_mfma(
    const ushort_t* __restrict__ AGG,
    const ushort_t* __restrict__ Ub, float* __restrict__ out)
{
    __shared__ ushort_t As[64 * 136];    // A tile: [node][k] bf16
    __shared__ ushort_t Bs[128 * 136];   // B tile: [i][k] bf16

    const int t    = threadIdx.x;
    const int lane = t & 63;
    const int w    = t >> 6;
    const int n0   = blockIdx.x * 64;

    f32x4 acc[8];
    #pragma unroll
    for (int f = 0; f < 8; f++) acc[f] = (f32x4){0.f, 0.f, 0.f, 0.f};

    for (int r = 0; r < N_REL; r++) {
        __syncthreads();

        {   // stage A: AGG[r][n0..n0+63][0..127] plain bf16 copy (16B chunks)
            const uint4* a4 = (const uint4*)(AGG + ((size_t)r * N_NODES + n0) * 128);
            for (int idx = t; idx < 64 * 16; idx += 256) {
                int nn = idx >> 4, c = idx & 15;
                uint4 v = make_uint4(0, 0, 0, 0);
                if (n0 + nn < N_NODES) v = a4[idx];
                *(uint4*)&As[nn * 136 + c * 8] = v;
            }
        }
        {   // stage B: Mb[r] straight copy (L2-hot)
            const uint4* u4 = (const uint4*)(Ub + (size_t)r * 128 * 128);
            for (int idx = t; idx < 128 * 16; idx += 256) {
                int i = idx >> 4, c = idx & 15;
                *(uint4*)&Bs[i * 136 + c * 8] = u4[idx];
            }
        }
        __syncthreads();

        const int row = lane & 15;     // A row / B col
        const int kg  = lane >> 4;     // k-group
        #pragma unroll
        for (int ks = 0; ks < 4; ks++) {
            const int kofs = ks * 32 + kg * 8;
            bf16x8 a = *(const bf16x8*)&As[(w * 16 + row) * 136 + kofs];
            #pragma unroll
            for (int f = 0; f < 8; f++) {
                bf16x8 b = *(const bf16x8*)&Bs[(f * 16 + row) * 136 + kofs];
                acc[f] = __builtin_amdgcn_mfma_f32_16x16x32_bf16(a, b, acc[f], 0, 0, 0);
            }
        }
    }

    const int col  = lane & 15;
    const int rgrp = lane >> 4;
    #pragma unroll
    for (int f = 0; f < 8; f++) {
        #pragma unroll
        for (int reg = 0; reg < 4; reg++) {
            int n = n0 + w * 16 + rgrp * 4 + reg;
            if (n < N_NODES)
                out[(size_t)n * 128 + f * 16 + col] = fmaxf(acc[f][reg], 0.f);
        }
    }
}

extern "C" void kernel_launch(void* const* d_in, const int* in_sizes, int n_in,
                              void* d_out, int out_size, void* d_ws, size_t ws_size,
                              hipStream_t stream)
{
    const float* x  = (const float*)d_in[0];
    const float* tk = (const float*)d_in[1];
    const float* tq = (const float*)d_in[2];
    const float* tv = (const float*)d_in[3];
    const float* un = (const float*)d_in[4];
    const int* esub  = (const int*)d_in[5];
    const int* epred = (const int*)d_in[6];
    const int* eobj  = (const int*)d_in[7];
    float* out = (float*)d_out;

    // Workspace layout (bytes), offsets identical to r12-16 (KT slot unused):
    //   (unused, was KT)                                 @ 0            (51,200,000)
    //   XB:   [N][128] bf16 (x cast — the gather target) @ 51,200,000   (12,800,000)
    //   AGG:  [R*N][128] bf16 (x-space aggregates)       @ 64,000,000   (51,200,000)
    //   HIST/CURSOR: [200000] int                        @ 115,200,000  (   800,000)
    //   SUMS: [196] int (pad 4096)                       @ 116,000,000  (     4,096)
    //   SOFF: [196] int (pad 4096)                       @ 116,004,096  (     4,096)
    //   OFFS: [200001] int                               @ 116,008,192  (   800,004 pad)
    //   OBJS: [400000] int                               @ 116,816,000  ( 1,600,000)
    //   Mb:   [R][128][128] bf16 (U·BD(tovals))          @ 118,416,000  (   131,072)
    //   Ct:   [R][H][32][32] bf16 (K^T Q bilinear)       @ 118,547,072  (    32,768)
    char* ws = (char*)d_ws;
    ushort_t* XB  = (ushort_t*)(ws + 51200000);
    ushort_t* AGG = (ushort_t*)(ws + 64000000);
    int*      HIST= (int*)     (ws + 115200000);   // doubles as CURSOR
    int*      SUMS= (int*)     (ws + 116000000);
    int*      SOFF= (int*)     (ws + 116004096);
    int*      OFFS= (int*)     (ws + 116008192);
    int*      OBJS= (int*)     (ws + 116816000);
    ushort_t* Mb  = (ushort_t*)(ws + 118416000);
    ushort_t* Ct  = (ushort_t*)(ws + 118547072);

    // prep (fused): x cast + HIST zero + Ct/Mb small-matrix products
    prep_kernel<<<(N_NODES * EMBD + 81920) / 256, 256, 0, stream>>>(
        x, tk, tq, tv, un, XB, HIST, Ct, Mb);

    // CSR build
    hist_kernel<<<(N_EDGE + 255) / 256, 256, 0, stream>>>(esub, epred, HIST);
    scan_p1<<<N_SBLK, 256, 0, stream>>>(HIST, SUMS);
    scan_p2<<<1, 256, 0, stream>>>(SUMS, SOFF, OFFS);
    scan_p3<<<N_SBLK, 256, 0, stream>>>(HIST, SOFF, OFFS, HIST);  // OFFS + CURSOR
    scatter_kernel<<<(N_EDGE + 255) / 256, 256, 0, stream>>>(esub, epred, eobj, HIST, OBJS);

    // fused proj + bilinear-dot + softmax + x-space aggregate
    // (Kt LDS-only; 16 waves/block, 2 rows per half-wave)
    projagg_fused<<<N_NODES / 16, 1024, 0, stream>>>(XB, Ct, OFFS, OBJS,
                                                     (const uint2*)XB, (uint2*)AGG);

    unify_mfma<<<(N_NODES + 63) / 64, 256, 0, stream>>>(AGG, Mb, out);
}

// Round 18
// 152.939 us; speedup vs baseline: 1.0672x; 1.0147x over previous
//
#include <hip/hip_runtime.h>

constexpr int N_NODES = 50000;
constexpr int N_REL   = 4;
constexpr int EMBD    = 128;
constexpr int N_HEAD  = 4;
constexpr int HS      = 32;
constexpr int N_EDGE  = 400000;
constexpr int N_ROWS  = N_REL * N_NODES;        // 200000 segment rows
constexpr int N_SBLK  = 196;                    // scan blocks (1024 rows each)

typedef __attribute__((ext_vector_type(8))) short bf16x8;
typedef __attribute__((ext_vector_type(4))) float f32x4;
typedef unsigned short ushort_t;
typedef unsigned int   uint_t;

__device__ __forceinline__ ushort_t f2b(float f) {
    unsigned int u = __float_as_uint(f);
    u += 0x7FFF + ((u >> 16) & 1);   // round-to-nearest-even
    return (ushort_t)(u >> 16);
}
__device__ __forceinline__ float lo_bf(uint_t u) {   // bf16 pair: low elem
    return __uint_as_float(u << 16);
}
__device__ __forceinline__ float hi_bf(uint_t u) {   // bf16 pair: high elem
    return __uint_as_float(u & 0xFFFF0000u);
}

// ---------------------------------------------------------------------------
// prep (fused): XB = bf16(x), HIST = 0, Ct = tokeys^T toqueries (per r,h),
// Mb = U·BD(tovals). KNOWN GOOD (r13-17).
// ---------------------------------------------------------------------------
__global__ __launch_bounds__(256) void prep_kernel(
    const float* __restrict__ x,
    const float* __restrict__ tk, const float* __restrict__ tq,
    const float* __restrict__ tv, const float* __restrict__ un,
    ushort_t* __restrict__ XB, int* __restrict__ HIST,
    ushort_t* __restrict__ Ct, ushort_t* __restrict__ Mb)
{
    int idx = blockIdx.x * 256 + threadIdx.x;      // grid 25320 = 6481920 threads
    if (idx < N_NODES * EMBD) {
        XB[idx] = f2b(x[idx]);
        if (idx < N_ROWS) HIST[idx] = 0;
    } else {
        int jj = idx - N_NODES * EMBD;             // < 81920
        if (jj < 16384) {
            int a = jj & 31, b = (jj >> 5) & 31, rh = jj >> 10;   // rh = r*4+h
            const float* tks = tk + rh * 1024;     // [s][a]
            const float* tqs = tq + rh * 1024;     // [s][b]
            float acc = 0.f;
            #pragma unroll
            for (int s = 0; s < 32; s++) acc += tks[s * 32 + a] * tqs[s * 32 + b];
            Ct[jj] = f2b(acc);                     // (rh*32 + b)*32 + a
        } else {
            int j  = jj - 16384;                   // Mb flat: [r][i][jc]
            int jc = j & 127, i = (j >> 7) & 127, r = j >> 14;
            int h = jc >> 5, k = jc & 31;
            const float* us  = un + ((size_t)(r * 128 + i)) * 128 + h * 32;
            const float* tvs = tv + (r * 4 + h) * 1024 + k;
            float acc = 0.f;
            #pragma unroll
            for (int s = 0; s < 32; s++) acc += us[s] * tvs[s * 32];
            Mb[j] = f2b(acc);
        }
    }
}

// ---------------------------------------------------------------------------
// CSR build: histogram -> 3-phase deterministic scan -> scatter. KNOWN GOOD.
// ---------------------------------------------------------------------------
__global__ __launch_bounds__(256) void hist_kernel(
    const int* __restrict__ esub, const int* __restrict__ epred, int* __restrict__ HIST)
{
    int e = blockIdx.x * 256 + threadIdx.x;
    if (e < N_EDGE) atomicAdd(&HIST[epred[e] * N_NODES + esub[e]], 1);
}

__global__ __launch_bounds__(256) void scan_p1(      // per-block totals
    const int* __restrict__ HIST, int* __restrict__ SUMS)
{
    int b = blockIdx.x, t = threadIdx.x;
    int base = b * 1024 + t * 4;
    int s = 0;
    #pragma unroll
    for (int k = 0; k < 4; k++) if (base + k < N_ROWS) s += HIST[base + k];
    __shared__ int red[256];
    red[t] = s; __syncthreads();
    for (int st = 128; st > 0; st >>= 1) {
        if (t < st) red[t] += red[t + st];
        __syncthreads();
    }
    if (t == 0) SUMS[b] = red[0];
}

__global__ __launch_bounds__(256) void scan_p2(      // scan the 196 totals
    const int* __restrict__ SUMS, int* __restrict__ SOFF, int* __restrict__ OFFS)
{
    int t = threadIdx.x;
    __shared__ int sh[256];
    int o = (t < N_SBLK) ? SUMS[t] : 0;
    sh[t] = o; __syncthreads();
    for (int st = 1; st < 256; st <<= 1) {
        int v = (t >= st) ? sh[t - st] : 0;
        __syncthreads();
        sh[t] += v;
        __syncthreads();
    }
    if (t < N_SBLK) SOFF[t] = sh[t] - o;             // exclusive
    if (t == 0)  OFFS[N_ROWS] = sh[255];             // total == N_EDGE
}

__global__ __launch_bounds__(256) void scan_p3(      // full exclusive scan (+CURSOR)
    const int* __restrict__ HIST, const int* __restrict__ SOFF,
    int* __restrict__ OFFS, int* __restrict__ CURSOR)
{
    int b = blockIdx.x, t = threadIdx.x;
    int base = b * 1024 + t * 4;
    int v[4], tot = 0;
    #pragma unroll
    for (int k = 0; k < 4; k++) {
        v[k] = (base + k < N_ROWS) ? HIST[base + k] : 0;
        tot += v[k];
    }
    __shared__ int sh[256];
    sh[t] = tot; __syncthreads();
    for (int st = 1; st < 256; st <<= 1) {
        int q = (t >= st) ? sh[t - st] : 0;
        __syncthreads();
        sh[t] += q;
        __syncthreads();
    }
    int run = SOFF[b] + (sh[t] - tot);
    #pragma unroll
    for (int k = 0; k < 4; k++) {
        if (base + k < N_ROWS) { OFFS[base + k] = run; CURSOR[base + k] = run; run += v[k]; }
    }
}

__global__ __launch_bounds__(256) void scatter_kernel(
    const int* __restrict__ esub, const int* __restrict__ epred, const int* __restrict__ eobj,
    int* __restrict__ CURSOR, int* __restrict__ OBJS)
{
    int e = blockIdx.x * 256 + threadIdx.x;
    if (e < N_EDGE) {
        int row = epred[e] * N_NODES + esub[e];
        int pos = atomicAdd(&CURSOR[row], 1);
        OBJS[pos] = eobj[e];                       // store obj, not edge id
    }
}

// ---------------------------------------------------------------------------
// FUSED projection + dot + softmax + aggregate, 512-thread blocks (8 waves).
// Block = 16 nodes x ONE relation (blockIdx.y) = 16 rows. Kt LDS-only.
//  Phase 1 (proj): wave w -> fragment f=w (h=f>>1, j=f&1): ONE MFMA per wave
//    (fragment maps + Ct addressing proven r12-17). D -> kt LDS (stride 132).
//  Phase 2 (agg): 16 half-waves x exactly ONE row (serial factor 1; r17 had
//    2 rows/half-wave and 64-row blocks -> block-max-degree drain).
//    Edge-loop body = r15/16/17 verbatim; Kt from 8B conflict-free LDS read.
// LDS ~8.6KB, 512 threads -> 4 blocks/CU = 32 waves (100%), 4x finer block
// retirement than r17's 16-wave blocks (51% occupancy, block-drain bound).
// xs is staged once per (tile, rel) = 4x redundant XB reads — L2-absorbed.
// ---------------------------------------------------------------------------
__global__ __launch_bounds__(512) void projagg_fused(
    const ushort_t* __restrict__ XB, const ushort_t* __restrict__ Ct,
    const int* __restrict__ OFFS, const int* __restrict__ OBJS,
    const uint2* __restrict__ XB128, uint2* __restrict__ AGG128)
{
    __shared__ __align__(16) ushort_t xs[16 * 136];   // x tile, proven pad
    __shared__ __align__(16) ushort_t kt[16 * 132];   // Kt[nl][128], pad 132

    const int t    = threadIdx.x;        // 0..511
    const int lane = t & 63;
    const int w    = t >> 6;             // wave 0..7
    const int n0   = blockIdx.x * 16;    // grid (3125, 4)
    const int rel  = blockIdx.y;

    {   // stage xs: 16 nodes x 128 bf16 = 4KB = 512 threads x 8B (one shot)
        const uint2* x2 = (const uint2*)(XB + (size_t)n0 * 128);
        int nn = t >> 5, c = t & 31;
        *(uint2*)&xs[nn * 136 + c * 4] = x2[t];
    }
    __syncthreads();

    {   // proj: wave w -> fragment f=w of this block's relation
        const int f   = w;
        const int h   = f >> 1;
        const int j   = f & 1;
        const int row = lane & 15;
        const int kg  = lane >> 4;
        bf16x8 a = *(const bf16x8*)&xs[row * 136 + h * 32 + kg * 8];
        const ushort_t* bp = Ct + (((rel * 4 + h) * 32 + j * 16 + row) * 32) + kg * 8;
        bf16x8 b = *(const bf16x8*)bp;
        f32x4 acc = __builtin_amdgcn_mfma_f32_16x16x32_bf16(
                        a, b, (f32x4){0.f, 0.f, 0.f, 0.f}, 0, 0, 0);
        #pragma unroll
        for (int reg = 0; reg < 4; reg++)
            kt[(kg * 4 + reg) * 132 + f * 16 + row] = f2b(acc[reg]);
    }
    __syncthreads();

    // agg: half-wave hw (0..15) handles exactly one row (node n0+hw)
    const int l5 = lane & 31;
    const int hw = t >> 5;
    const int row = rel * N_NODES + n0 + hw;
    const int beg = OFFS[row], end = OFFS[row + 1];   // half-uniform
    const bool has = beg < end;

    float k0 = 0.f, k1 = 0.f, k2 = 0.f, k3 = 0.f;
    if (has) {
        uint2 ku = *(const uint2*)&kt[hw * 132 + l5 * 4];
        k0 = lo_bf(ku.x); k1 = hi_bf(ku.x); k2 = lo_bf(ku.y); k3 = hi_bf(ku.y);
    }

    float a0 = 0.f, a1 = 0.f, a2 = 0.f, a3 = 0.f, seg = 0.f;
    int it = beg;
    while (__any(it < end)) {                   // wave-uniform loop bound
        const bool d0 = it < end;               // half-uniform guards
        const bool d1 = it + 1 < end;
        uint2 xu0 = make_uint2(0u, 0u), xu1 = make_uint2(0u, 0u);
        if (d0) xu0 = XB128[(unsigned)OBJS[it] * 32u + l5];
        if (d1) xu1 = XB128[(unsigned)OBJS[it + 1] * 32u + l5];

        float x00 = lo_bf(xu0.x), x01 = hi_bf(xu0.x), x02 = lo_bf(xu0.y), x03 = hi_bf(xu0.y);
        float x10 = lo_bf(xu1.x), x11 = hi_bf(xu1.x), x12 = lo_bf(xu1.y), x13 = hi_bf(xu1.y);

        float p0 = k0 * x00 + k1 * x01 + k2 * x02 + k3 * x03;
        float p1 = k0 * x10 + k1 * x11 + k2 * x12 + k3 * x13;
        p0 += __shfl_xor(p0, 1, 64); p1 += __shfl_xor(p1, 1, 64);
        p0 += __shfl_xor(p0, 2, 64); p1 += __shfl_xor(p1, 2, 64);
        p0 += __shfl_xor(p0, 4, 64); p1 += __shfl_xor(p1, 4, 64);
        float ex0 = __expf(p0), ex1 = __expf(p1);

        int adv = 0;
        if (d0) { a0 += ex0 * x00; a1 += ex0 * x01; a2 += ex0 * x02; a3 += ex0 * x03; seg += ex0; adv = 1; }
        if (d1) { a0 += ex1 * x10; a1 += ex1 * x11; a2 += ex1 * x12; a3 += ex1 * x13; seg += ex1; adv = 2; }
        it += adv;
    }

    uint2 o = make_uint2(0u, 0u);
    if (has) {
        float inv = 1.0f / seg;
        o.x = (uint_t)f2b(a0 * inv) | ((uint_t)f2b(a1 * inv) << 16);
        o.y = (uint_t)f2b(a2 * inv) | ((uint_t)f2b(a3 * inv) << 16);
    }
    AGG128[(unsigned)row * 32u + l5] = o;
}

// ---------------------------------------------------------------------------
// out[n][i] = relu( sum_r sum_j M[r][i][j] * AGGX[r][n][j] )  — bf16 MFMA,
// fp32 accum. KNOWN GOOD (rounds 5-17); B = Mb (U·BD(tovals)).
// ---------------------------------------------------------------------------
__global__ __launch_bounds__(256) void unify_mfma(
    const ushort_t* __restrict__ AGG,
    const ushort_t* __restrict__ Ub, float* __restrict__ out)
{
    __shared__ ushort_t As[64 * 136];    // A tile: [node][k] bf16
    __shared__ ushort_t Bs[128 * 136];   // B tile: [i][k] bf16

    const int t    = threadIdx.x;
    const int lane = t & 63;
    const int w    = t >> 6;
    const int n0   = blockIdx.x * 64;

    f32x4 acc[8];
    #pragma unroll
    for (int f = 0; f < 8; f++) acc[f] = (f32x4){0.f, 0.f, 0.f, 0.f};

    for (int r = 0; r < N_REL; r++) {
        __syncthreads();

        {   // stage A: AGG[r][n0..n0+63][0..127] plain bf16 copy (16B chunks)
            const uint4* a4 = (const uint4*)(AGG + ((size_t)r * N_NODES + n0) * 128);
            for (int idx = t; idx < 64 * 16; idx += 256) {
                int nn = idx >> 4, c = idx & 15;
                uint4 v = make_uint4(0, 0, 0, 0);
                if (n0 + nn < N_NODES) v = a4[idx];
                *(uint4*)&As[nn * 136 + c * 8] = v;
            }
        }
        {   // stage B: Mb[r] straight copy (L2-hot)
            const uint4* u4 = (const uint4*)(Ub + (size_t)r * 128 * 128);
            for (int idx = t; idx < 128 * 16; idx += 256) {
                int i = idx >> 4, c = idx & 15;
                *(uint4*)&Bs[i * 136 + c * 8] = u4[idx];
            }
        }
        __syncthreads();

        const int row = lane & 15;     // A row / B col
        const int kg  = lane >> 4;     // k-group
        #pragma unroll
        for (int ks = 0; ks < 4; ks++) {
            const int kofs = ks * 32 + kg * 8;
            bf16x8 a = *(const bf16x8*)&As[(w * 16 + row) * 136 + kofs];
            #pragma unroll
            for (int f = 0; f < 8; f++) {
                bf16x8 b = *(const bf16x8*)&Bs[(f * 16 + row) * 136 + kofs];
                acc[f] = __builtin_amdgcn_mfma_f32_16x16x32_bf16(a, b, acc[f], 0, 0, 0);
            }
        }
    }

    const int col  = lane & 15;
    const int rgrp = lane >> 4;
    #pragma unroll
    for (int f = 0; f < 8; f++) {
        #pragma unroll
        for (int reg = 0; reg < 4; reg++) {
            int n = n0 + w * 16 + rgrp * 4 + reg;
            if (n < N_NODES)
                out[(size_t)n * 128 + f * 16 + col] = fmaxf(acc[f][reg], 0.f);
        }
    }
}

extern "C" void kernel_launch(void* const* d_in, const int* in_sizes, int n_in,
                              void* d_out, int out_size, void* d_ws, size_t ws_size,
                              hipStream_t stream)
{
    const float* x  = (const float*)d_in[0];
    const float* tk = (const float*)d_in[1];
    const float* tq = (const float*)d_in[2];
    const float* tv = (const float*)d_in[3];
    const float* un = (const float*)d_in[4];
    const int* esub  = (const int*)d_in[5];
    const int* epred = (const int*)d_in[6];
    const int* eobj  = (const int*)d_in[7];
    float* out = (float*)d_out;

    // Workspace layout (bytes), offsets identical to r12-17 (KT slot unused):
    //   (unused, was KT)                                 @ 0            (51,200,000)
    //   XB:   [N][128] bf16 (x cast — the gather target) @ 51,200,000   (12,800,000)
    //   AGG:  [R*N][128] bf16 (x-space aggregates)       @ 64,000,000   (51,200,000)
    //   HIST/CURSOR: [200000] int                        @ 115,200,000  (   800,000)
    //   SUMS: [196] int (pad 4096)                       @ 116,000,000  (     4,096)
    //   SOFF: [196] int (pad 4096)                       @ 116,004,096  (     4,096)
    //   OFFS: [200001] int                               @ 116,008,192  (   800,004 pad)
    //   OBJS: [400000] int                               @ 116,816,000  ( 1,600,000)
    //   Mb:   [R][128][128] bf16 (U·BD(tovals))          @ 118,416,000  (   131,072)
    //   Ct:   [R][H][32][32] bf16 (K^T Q bilinear)       @ 118,547,072  (    32,768)
    char* ws = (char*)d_ws;
    ushort_t* XB  = (ushort_t*)(ws + 51200000);
    ushort_t* AGG = (ushort_t*)(ws + 64000000);
    int*      HIST= (int*)     (ws + 115200000);   // doubles as CURSOR
    int*      SUMS= (int*)     (ws + 116000000);
    int*      SOFF= (int*)     (ws + 116004096);
    int*      OFFS= (int*)     (ws + 116008192);
    int*      OBJS= (int*)     (ws + 116816000);
    ushort_t* Mb  = (ushort_t*)(ws + 118416000);
    ushort_t* Ct  = (ushort_t*)(ws + 118547072);

    // prep (fused): x cast + HIST zero + Ct/Mb small-matrix products
    prep_kernel<<<(N_NODES * EMBD + 81920) / 256, 256, 0, stream>>>(
        x, tk, tq, tv, un, XB, HIST, Ct, Mb);

    // CSR build
    hist_kernel<<<(N_EDGE + 255) / 256, 256, 0, stream>>>(esub, epred, HIST);
    scan_p1<<<N_SBLK, 256, 0, stream>>>(HIST, SUMS);
    scan_p2<<<1, 256, 0, stream>>>(SUMS, SOFF, OFFS);
    scan_p3<<<N_SBLK, 256, 0, stream>>>(HIST, SOFF, OFFS, HIST);  // OFFS + CURSOR
    scatter_kernel<<<(N_EDGE + 255) / 256, 256, 0, stream>>>(esub, epred, eobj, HIST, OBJS);

    // fused proj + bilinear-dot + softmax + x-space aggregate
    // (Kt LDS-only; 512-thread blocks, 1 row per half-wave, block = 16 nodes x 1 rel)
    projagg_fused<<<dim3(N_NODES / 16, N_REL), 512, 0, stream>>>(
        XB, Ct, OFFS, OBJS, (const uint2*)XB, (uint2*)AGG);

    unify_mfma<<<(N_NODES + 63) / 64, 256, 0, stream>>>(AGG, Mb, out);
}

// Round 19
// 152.430 us; speedup vs baseline: 1.0707x; 1.0033x over previous
//
#include <hip/hip_runtime.h>

constexpr int N_NODES = 50000;
constexpr int N_REL   = 4;
constexpr int EMBD    = 128;
constexpr int N_HEAD  = 4;
constexpr int HS      = 32;
constexpr int N_EDGE  = 400000;
constexpr int N_ROWS  = N_REL * N_NODES;        // 200000 segment rows
constexpr int N_SBLK  = 196;                    // scan blocks (1024 rows each)

typedef __attribute__((ext_vector_type(8))) short bf16x8;
typedef __attribute__((ext_vector_type(4))) float f32x4;
typedef unsigned short ushort_t;
typedef unsigned int   uint_t;

__device__ __forceinline__ ushort_t f2b(float f) {
    unsigned int u = __float_as_uint(f);
    u += 0x7FFF + ((u >> 16) & 1);   // round-to-nearest-even
    return (ushort_t)(u >> 16);
}
__device__ __forceinline__ float lo_bf(uint_t u) {   // bf16 pair: low elem
    return __uint_as_float(u << 16);
}
__device__ __forceinline__ float hi_bf(uint_t u) {   // bf16 pair: high elem
    return __uint_as_float(u & 0xFFFF0000u);
}

// ---------------------------------------------------------------------------
// prep (fused): XB = bf16(x), HIST = 0, Ct = tokeys^T toqueries (per r,h),
// Mb = U·BD(tovals). KNOWN GOOD (r13-18).
// ---------------------------------------------------------------------------
__global__ __launch_bounds__(256) void prep_kernel(
    const float* __restrict__ x,
    const float* __restrict__ tk, const float* __restrict__ tq,
    const float* __restrict__ tv, const float* __restrict__ un,
    ushort_t* __restrict__ XB, int* __restrict__ HIST,
    ushort_t* __restrict__ Ct, ushort_t* __restrict__ Mb)
{
    int idx = blockIdx.x * 256 + threadIdx.x;      // grid 25320 = 6481920 threads
    if (idx < N_NODES * EMBD) {
        XB[idx] = f2b(x[idx]);
        if (idx < N_ROWS) HIST[idx] = 0;
    } else {
        int jj = idx - N_NODES * EMBD;             // < 81920
        if (jj < 16384) {
            int a = jj & 31, b = (jj >> 5) & 31, rh = jj >> 10;   // rh = r*4+h
            const float* tks = tk + rh * 1024;     // [s][a]
            const float* tqs = tq + rh * 1024;     // [s][b]
            float acc = 0.f;
            #pragma unroll
            for (int s = 0; s < 32; s++) acc += tks[s * 32 + a] * tqs[s * 32 + b];
            Ct[jj] = f2b(acc);                     // (rh*32 + b)*32 + a
        } else {
            int j  = jj - 16384;                   // Mb flat: [r][i][jc]
            int jc = j & 127, i = (j >> 7) & 127, r = j >> 14;
            int h = jc >> 5, k = jc & 31;
            const float* us  = un + ((size_t)(r * 128 + i)) * 128 + h * 32;
            const float* tvs = tv + (r * 4 + h) * 1024 + k;
            float acc = 0.f;
            #pragma unroll
            for (int s = 0; s < 32; s++) acc += us[s] * tvs[s * 32];
            Mb[j] = f2b(acc);
        }
    }
}

// ---------------------------------------------------------------------------
// CSR build: histogram -> 2-phase deterministic scan -> scatter.
// (scan_p2 folded into scan_p3: each block self-scans the 196 SUMS in LDS —
//  196 loads + one 256-wide scan, trivial vs a dedicated launch.)
// ---------------------------------------------------------------------------
__global__ __launch_bounds__(256) void hist_kernel(
    const int* __restrict__ esub, const int* __restrict__ epred, int* __restrict__ HIST)
{
    int e = blockIdx.x * 256 + threadIdx.x;
    if (e < N_EDGE) atomicAdd(&HIST[epred[e] * N_NODES + esub[e]], 1);
}

__global__ __launch_bounds__(256) void scan_p1(      // per-block totals
    const int* __restrict__ HIST, int* __restrict__ SUMS)
{
    int b = blockIdx.x, t = threadIdx.x;
    int base = b * 1024 + t * 4;
    int s = 0;
    #pragma unroll
    for (int k = 0; k < 4; k++) if (base + k < N_ROWS) s += HIST[base + k];
    __shared__ int red[256];
    red[t] = s; __syncthreads();
    for (int st = 128; st > 0; st >>= 1) {
        if (t < st) red[t] += red[t + st];
        __syncthreads();
    }
    if (t == 0) SUMS[b] = red[0];
}

__global__ __launch_bounds__(256) void scan_p3(      // full exclusive scan (+CURSOR)
    const int* __restrict__ HIST, const int* __restrict__ SUMS,
    int* __restrict__ OFFS, int* __restrict__ CURSOR)
{
    int b = blockIdx.x, t = threadIdx.x;

    // inline scan of the 196 block totals (was scan_p2)
    __shared__ int gsh[256];
    __shared__ int gex[256];
    int go = (t < N_SBLK) ? SUMS[t] : 0;
    gsh[t] = go; __syncthreads();
    for (int st = 1; st < 256; st <<= 1) {
        int v = (t >= st) ? gsh[t - st] : 0;
        __syncthreads();
        gsh[t] += v;
        __syncthreads();
    }
    gex[t] = gsh[t] - go;                            // exclusive prefix
    if (b == 0 && t == 255) OFFS[N_ROWS] = gsh[255]; // total == N_EDGE
    __syncthreads();
    const int soff = gex[b];

    // per-block scan of HIST (original p3 body)
    int base = b * 1024 + t * 4;
    int v[4], tot = 0;
    #pragma unroll
    for (int k = 0; k < 4; k++) {
        v[k] = (base + k < N_ROWS) ? HIST[base + k] : 0;
        tot += v[k];
    }
    __shared__ int sh[256];
    sh[t] = tot; __syncthreads();
    for (int st = 1; st < 256; st <<= 1) {
        int q = (t >= st) ? sh[t - st] : 0;
        __syncthreads();
        sh[t] += q;
        __syncthreads();
    }
    int run = soff + (sh[t] - tot);
    #pragma unroll
    for (int k = 0; k < 4; k++) {
        if (base + k < N_ROWS) { OFFS[base + k] = run; CURSOR[base + k] = run; run += v[k]; }
    }
}

__global__ __launch_bounds__(256) void scatter_kernel(
    const int* __restrict__ esub, const int* __restrict__ epred, const int* __restrict__ eobj,
    int* __restrict__ CURSOR, int* __restrict__ OBJS)
{
    int e = blockIdx.x * 256 + threadIdx.x;
    if (e < N_EDGE) {
        int row = epred[e] * N_NODES + esub[e];
        int pos = atomicAdd(&CURSOR[row], 1);
        OBJS[pos] = eobj[e];                       // store obj, not edge id
    }
}

// ---------------------------------------------------------------------------
// FUSED projection + dot + softmax + aggregate, 512-thread blocks (8 waves).
// Block = 16 nodes x ONE relation = 16 rows; Kt LDS-only. KNOWN GOOD (r18).
// Grid TRANSPOSED vs r18: rel = blockIdx.x (fastest-varying) so the 4
// consecutive blocks share one x-tile -> xs staging hits L2/L1 (r18 re-read
// XB 4x from HBM: FETCH 48.7->63.7MB).
//  Phase 1 (proj): wave w -> fragment f=w (h=f>>1, j=f&1): ONE MFMA per wave.
//  Phase 2 (agg): 16 half-waves x exactly ONE row; edge-loop = r15-18 verbatim.
// ---------------------------------------------------------------------------
__global__ __launch_bounds__(512) void projagg_fused(
    const ushort_t* __restrict__ XB, const ushort_t* __restrict__ Ct,
    const int* __restrict__ OFFS, const int* __restrict__ OBJS,
    const uint2* __restrict__ XB128, uint2* __restrict__ AGG128)
{
    __shared__ __align__(16) ushort_t xs[16 * 136];   // x tile, proven pad
    __shared__ __align__(16) ushort_t kt[16 * 132];   // Kt[nl][128], pad 132

    const int t    = threadIdx.x;        // 0..511
    const int lane = t & 63;
    const int w    = t >> 6;             // wave 0..7
    const int rel  = blockIdx.x;         // grid (4, 3125) — rel varies fastest
    const int n0   = blockIdx.y * 16;

    {   // stage xs: 16 nodes x 128 bf16 = 4KB = 512 threads x 8B (one shot)
        const uint2* x2 = (const uint2*)(XB + (size_t)n0 * 128);
        int nn = t >> 5, c = t & 31;
        *(uint2*)&xs[nn * 136 + c * 4] = x2[t];
    }
    __syncthreads();

    {   // proj: wave w -> fragment f=w of this block's relation
        const int f   = w;
        const int h   = f >> 1;
        const int j   = f & 1;
        const int row = lane & 15;
        const int kg  = lane >> 4;
        bf16x8 a = *(const bf16x8*)&xs[row * 136 + h * 32 + kg * 8];
        const ushort_t* bp = Ct + (((rel * 4 + h) * 32 + j * 16 + row) * 32) + kg * 8;
        bf16x8 b = *(const bf16x8*)bp;
        f32x4 acc = __builtin_amdgcn_mfma_f32_16x16x32_bf16(
                        a, b, (f32x4){0.f, 0.f, 0.f, 0.f}, 0, 0, 0);
        #pragma unroll
        for (int reg = 0; reg < 4; reg++)
            kt[(kg * 4 + reg) * 132 + f * 16 + row] = f2b(acc[reg]);
    }
    __syncthreads();

    // agg: half-wave hw (0..15) handles exactly one row (node n0+hw)
    const int l5 = lane & 31;
    const int hw = t >> 5;
    const int row = rel * N_NODES + n0 + hw;
    const int beg = OFFS[row], end = OFFS[row + 1];   // half-uniform
    const bool has = beg < end;

    float k0 = 0.f, k1 = 0.f, k2 = 0.f, k3 = 0.f;
    if (has) {
        uint2 ku = *(const uint2*)&kt[hw * 132 + l5 * 4];
        k0 = lo_bf(ku.x); k1 = hi_bf(ku.x); k2 = lo_bf(ku.y); k3 = hi_bf(ku.y);
    }

    float a0 = 0.f, a1 = 0.f, a2 = 0.f, a3 = 0.f, seg = 0.f;
    int it = beg;
    while (__any(it < end)) {                   // wave-uniform loop bound
        const bool d0 = it < end;               // half-uniform guards
        const bool d1 = it + 1 < end;
        uint2 xu0 = make_uint2(0u, 0u), xu1 = make_uint2(0u, 0u);
        if (d0) xu0 = XB128[(unsigned)OBJS[it] * 32u + l5];
        if (d1) xu1 = XB128[(unsigned)OBJS[it + 1] * 32u + l5];

        float x00 = lo_bf(xu0.x), x01 = hi_bf(xu0.x), x02 = lo_bf(xu0.y), x03 = hi_bf(xu0.y);
        float x10 = lo_bf(xu1.x), x11 = hi_bf(xu1.x), x12 = lo_bf(xu1.y), x13 = hi_bf(xu1.y);

        float p0 = k0 * x00 + k1 * x01 + k2 * x02 + k3 * x03;
        float p1 = k0 * x10 + k1 * x11 + k2 * x12 + k3 * x13;
        p0 += __shfl_xor(p0, 1, 64); p1 += __shfl_xor(p1, 1, 64);
        p0 += __shfl_xor(p0, 2, 64); p1 += __shfl_xor(p1, 2, 64);
        p0 += __shfl_xor(p0, 4, 64); p1 += __shfl_xor(p1, 4, 64);
        float ex0 = __expf(p0), ex1 = __expf(p1);

        int adv = 0;
        if (d0) { a0 += ex0 * x00; a1 += ex0 * x01; a2 += ex0 * x02; a3 += ex0 * x03; seg += ex0; adv = 1; }
        if (d1) { a0 += ex1 * x10; a1 += ex1 * x11; a2 += ex1 * x12; a3 += ex1 * x13; seg += ex1; adv = 2; }
        it += adv;
    }

    uint2 o = make_uint2(0u, 0u);
    if (has) {
        float inv = 1.0f / seg;
        o.x = (uint_t)f2b(a0 * inv) | ((uint_t)f2b(a1 * inv) << 16);
        o.y = (uint_t)f2b(a2 * inv) | ((uint_t)f2b(a3 * inv) << 16);
    }
    AGG128[(unsigned)row * 32u + l5] = o;
}

// ---------------------------------------------------------------------------
// out[n][i] = relu( sum_r sum_j M[r][i][j] * AGGX[r][n][j] )  — bf16 MFMA,
// fp32 accum. KNOWN GOOD (rounds 5-18); B = Mb (U·BD(tovals)).
// ---------------------------------------------------------------------------
__global__ __launch_bounds__(256) void unify_mfma(
    const ushort_t* __restrict__ AGG,
    const ushort_t* __restrict__ Ub, float* __restrict__ out)
{
    __shared__ ushort_t As[64 * 136];    // A tile: [node][k] bf16
    __shared__ ushort_t Bs[128 * 136];   // B tile: [i][k] bf16

    const int t    = threadIdx.x;
    const int lane = t & 63;
    const int w    = t >> 6;
    const int n0   = blockIdx.x * 64;

    f32x4 acc[8];
    #pragma unroll
    for (int f = 0; f < 8; f++) acc[f] = (f32x4){0.f, 0.f, 0.f, 0.f};

    for (int r = 0; r < N_REL; r++) {
        __syncthreads();

        {   // stage A: AGG[r][n0..n0+63][0..127] plain bf16 copy (16B chunks)
            const uint4* a4 = (const uint4*)(AGG + ((size_t)r * N_NODES + n0) * 128);
            for (int idx = t; idx < 64 * 16; idx += 256) {
                int nn = idx >> 4, c = idx & 15;
                uint4 v = make_uint4(0, 0, 0, 0);
                if (n0 + nn < N_NODES) v = a4[idx];
                *(uint4*)&As[nn * 136 + c * 8] = v;
            }
        }
        {   // stage B: Mb[r] straight copy (L2-hot)
            const uint4* u4 = (const uint4*)(Ub + (size_t)r * 128 * 128);
            for (int idx = t; idx < 128 * 16; idx += 256) {
                int i = idx >> 4, c = idx & 15;
                *(uint4*)&Bs[i * 136 + c * 8] = u4[idx];
            }
        }
        __syncthreads();

        const int row = lane & 15;     // A row / B col
        const int kg  = lane >> 4;     // k-group
        #pragma unroll
        for (int ks = 0; ks < 4; ks++) {
            const int kofs = ks * 32 + kg * 8;
            bf16x8 a = *(const bf16x8*)&As[(w * 16 + row) * 136 + kofs];
            #pragma unroll
            for (int f = 0; f < 8; f++) {
                bf16x8 b = *(const bf16x8*)&Bs[(f * 16 + row) * 136 + kofs];
                acc[f] = __builtin_amdgcn_mfma_f32_16x16x32_bf16(a, b, acc[f], 0, 0, 0);
            }
        }
    }

    const int col  = lane & 15;
    const int rgrp = lane >> 4;
    #pragma unroll
    for (int f = 0; f < 8; f++) {
        #pragma unroll
        for (int reg = 0; reg < 4; reg++) {
            int n = n0 + w * 16 + rgrp * 4 + reg;
            if (n < N_NODES)
                out[(size_t)n * 128 + f * 16 + col] = fmaxf(acc[f][reg], 0.f);
        }
    }
}

extern "C" void kernel_launch(void* const* d_in, const int* in_sizes, int n_in,
                              void* d_out, int out_size, void* d_ws, size_t ws_size,
                              hipStream_t stream)
{
    const float* x  = (const float*)d_in[0];
    const float* tk = (const float*)d_in[1];
    const float* tq = (const float*)d_in[2];
    const float* tv = (const float*)d_in[3];
    const float* un = (const float*)d_in[4];
    const int* esub  = (const int*)d_in[5];
    const int* epred = (const int*)d_in[6];
    const int* eobj  = (const int*)d_in[7];
    float* out = (float*)d_out;

    // Workspace layout (bytes), offsets identical to r12-18 (SOFF slot unused):
    //   (unused, was KT)                                 @ 0            (51,200,000)
    //   XB:   [N][128] bf16 (x cast — the gather target) @ 51,200,000   (12,800,000)
    //   AGG:  [R*N][128] bf16 (x-space aggregates)       @ 64,000,000   (51,200,000)
    //   HIST/CURSOR: [200000] int                        @ 115,200,000  (   800,000)
    //   SUMS: [196] int (pad 4096)                       @ 116,000,000  (     4,096)
    //   (unused, was SOFF)                               @ 116,004,096  (     4,096)
    //   OFFS: [200001] int                               @ 116,008,192  (   800,004 pad)
    //   OBJS: [400000] int                               @ 116,816,000  ( 1,600,000)
    //   Mb:   [R][128][128] bf16 (U·BD(tovals))          @ 118,416,000  (   131,072)
    //   Ct:   [R][H][32][32] bf16 (K^T Q bilinear)       @ 118,547,072  (    32,768)
    char* ws = (char*)d_ws;
    ushort_t* XB  = (ushort_t*)(ws + 51200000);
    ushort_t* AGG = (ushort_t*)(ws + 64000000);
    int*      HIST= (int*)     (ws + 115200000);   // doubles as CURSOR
    int*      SUMS= (int*)     (ws + 116000000);
    int*      OFFS= (int*)     (ws + 116008192);
    int*      OBJS= (int*)     (ws + 116816000);
    ushort_t* Mb  = (ushort_t*)(ws + 118416000);
    ushort_t* Ct  = (ushort_t*)(ws + 118547072);

    // prep (fused): x cast + HIST zero + Ct/Mb small-matrix products
    prep_kernel<<<(N_NODES * EMBD + 81920) / 256, 256, 0, stream>>>(
        x, tk, tq, tv, un, XB, HIST, Ct, Mb);

    // CSR build (scan_p2 folded into scan_p3)
    hist_kernel<<<(N_EDGE + 255) / 256, 256, 0, stream>>>(esub, epred, HIST);
    scan_p1<<<N_SBLK, 256, 0, stream>>>(HIST, SUMS);
    scan_p3<<<N_SBLK, 256, 0, stream>>>(HIST, SUMS, OFFS, HIST);  // OFFS + CURSOR
    scatter_kernel<<<(N_EDGE + 255) / 256, 256, 0, stream>>>(esub, epred, eobj, HIST, OBJS);

    // fused proj + bilinear-dot + softmax + x-space aggregate
    // (rel fastest-varying in grid -> 4 consecutive blocks share one x-tile)
    projagg_fused<<<dim3(N_REL, N_NODES / 16), 512, 0, stream>>>(
        XB, Ct, OFFS, OBJS, (const uint2*)XB, (uint2*)AGG);

    unify_mfma<<<(N_NODES + 63) / 64, 256, 0, stream>>>(AGG, Mb, out);
}